// Round 14
// baseline (2690.452 us; speedup 1.0000x reference)
//
#include <hip/hip_runtime.h>

typedef unsigned int u32;
typedef u32 u32x8 __attribute__((ext_vector_type(8)));

#define TT 2048
#define HD 256
#define G4 1024
#define NT 16
#define START_TAG 14
#define STOP_TAG 15
#define NEGV (-10000.0f)

__device__ __forceinline__ int sdot4e(u32 a, u32 b, int c) {
#if __has_builtin(__builtin_amdgcn_sdot4)
    return __builtin_amdgcn_sdot4((int)a, (int)b, c, false);
#else
    c += (int)(signed char)(a & 255) * (int)(signed char)(b & 255);
    c += (int)(signed char)((a >> 8) & 255) * (int)(signed char)((b >> 8) & 255);
    c += (int)(signed char)((a >> 16) & 255) * (int)(signed char)((b >> 16) & 255);
    c += (int)(signed char)(a >> 24) * (int)(signed char)(b >> 24);
    return c;
#endif
}
__device__ __forceinline__ float sigmf_(float x) { return 1.0f / (1.0f + __expf(-x)); }
__device__ __forceinline__ float tanhf_(float x) {
    float e = __expf(-2.0f * fabsf(x));
    return copysignf((1.0f - e) / (1.0f + e), x);
}

// K0: quantize w_hh to int8, per-row scale -> wreg8[dir][row][64] + rowscale.
__global__ __launch_bounds__(256) void pack_q8(const float* whh_f, const float* whh_b,
                                               u32* wreg8, float* rowscale) {
    int lane = threadIdx.x & 63;
    int row = blockIdx.x * 4 + (threadIdx.x >> 6);   // 0..2047
    int dir = row >> 10, r = row & 1023;
    const float* w = (dir ? whh_b : whh_f) + (size_t)r * HD + lane * 4;
    float4 v = *((const float4*)w);
    float m = fmaxf(fmaxf(fabsf(v.x), fabsf(v.y)), fmaxf(fabsf(v.z), fabsf(v.w)));
    for (int off = 1; off < 64; off <<= 1) m = fmaxf(m, __shfl_xor(m, off, 64));
    float invs = m > 0.f ? 127.f / m : 0.f;
    int q0 = (int)rintf(v.x * invs), q1 = (int)rintf(v.y * invs);
    int q2 = (int)rintf(v.z * invs), q3 = (int)rintf(v.w * invs);
    u32 pk = (u32)(q0 & 255) | ((u32)(q1 & 255) << 8) |
             ((u32)(q2 & 255) << 16) | ((u32)(q3 & 255) << 24);
    wreg8[((size_t)(dir * 1024 + r)) * 64 + lane] = pk;
    if (lane == 0) rowscale[dir * 1024 + r] = m * (1.0f / (127.f * 64.f));
}

// K1: G[dir][t][r] = dot(embed[sent[t or T-1-t]], w_ih[r]) + b[r]   (f32 exact)
__global__ __launch_bounds__(256) void input_gemm(const int* sent, const float* embed,
                                                  const float* wih_f, const float* b_f,
                                                  const float* wih_b, const float* b_b,
                                                  float* G) {
    __shared__ float X[16][HD];   // 16KB
    __shared__ int rows[16];
    int tid = threadIdx.x;
    int dir = blockIdx.z;
    int t0 = blockIdx.x * 16;
    if (tid < 16) {
        int tg = t0 + tid;
        rows[tid] = sent[dir ? (TT - 1 - tg) : tg];
    }
    __syncthreads();
    for (int i = 0; i < 16; i++) X[i][tid] = embed[(size_t)rows[i] * HD + tid];
    __syncthreads();
    int r = blockIdx.y * 256 + tid;
    const float* wrow = (dir ? wih_b : wih_f) + (size_t)r * HD;
    float acc[16];
#pragma unroll
    for (int i = 0; i < 16; i++) acc[i] = 0.0f;
    for (int kc = 0; kc < HD / 4; kc++) {
        float4 w4 = ((const float4*)wrow)[kc];
#pragma unroll
        for (int i = 0; i < 16; i++) {
            float4 x4 = *((const float4*)&X[i][kc * 4]);
            acc[i] += w4.x * x4.x + w4.y * x4.y + w4.z * x4.z + w4.w * x4.w;
        }
    }
    float bias = (dir ? b_b : b_f)[r];
    for (int i = 0; i < 16; i++)
        G[((size_t)dir * TT + t0 + i) * G4 + r] = acc[i] + bias;
}

// two-row int8 dot block vs h broadcast at hbp[HB..HB+7]
#define DOTQ2(W0, W1, HB)                                                     \
    {                                                                         \
        uint4 pa = *((const uint4*)&hbp[(HB)]);                               \
        acc0 = sdot4e(W0[0], pa.x, acc0); acc1 = sdot4e(W1[0], pa.x, acc1);   \
        acc0 = sdot4e(W0[1], pa.y, acc0); acc1 = sdot4e(W1[1], pa.y, acc1);   \
        acc0 = sdot4e(W0[2], pa.z, acc0); acc1 = sdot4e(W1[2], pa.z, acc1);   \
        acc0 = sdot4e(W0[3], pa.w, acc0); acc1 = sdot4e(W1[3], pa.w, acc1);   \
        uint4 pb = *((const uint4*)&hbp[(HB) + 4]);                           \
        acc0 = sdot4e(W0[4], pb.x, acc0); acc1 = sdot4e(W1[4], pb.x, acc1);   \
        acc0 = sdot4e(W0[5], pb.y, acc0); acc1 = sdot4e(W1[5], pb.y, acc1);   \
        acc0 = sdot4e(W0[6], pb.z, acc0); acc1 = sdot4e(W1[6], pb.z, acc1);   \
        acc0 = sdot4e(W0[7], pb.w, acc0); acc1 = sdot4e(W1[7], pb.w, acc1);   \
    }

// K2: persistent per-direction LSTM recurrence, int8 (v_dot4), 512 threads.
// INTRA-WAVE gate pairing: wave w covers elems e = w*32..w*32+31; lane<32 owns
// rows (i_e, g_e), lane>=32 owns (f_e, o_e) -> gate exchange is 2x shfl_xor(32)
// in-wave, no LDS round-trip, and the step needs ONE barrier (h2q parity-dbuf,
// R10-validated). All 128 weight u32 in 16 named u32x8 SSA values (VGPR+AGPR,
// R13-measured scratch-free). Arithmetic element-identical to R13.
__global__ __launch_bounds__(512, 1)
void lstm_rec(const u32* wreg8, const float* rowscale,
              const float* G, const float* h0, const float* c0, float* H) {
    __shared__ __align__(16) u32 h2q[2][64];   // parity-dbuf 256 int8 of h
    int tid = threadIdx.x;
    int lane = tid & 63;
    int wv = tid >> 6;
    int lo = lane & 31;
    int half = lane >> 5;                      // 0: (i,g)  1: (f,o)
    int e = wv * 32 + lo;                      // element 0..255
    int row0 = half * 256 + e;                 // i_e or f_e
    int row1 = row0 + 512;                     // g_e or o_e
    int dir = blockIdx.x;
    const u32x8* p0 = (const u32x8*)(wreg8 + ((size_t)dir * 1024 + row0) * 64);
    const u32x8* p1 = (const u32x8*)(wreg8 + ((size_t)dir * 1024 + row1) * 64);
    u32x8 wq00 = p0[0], wq01 = p0[1], wq02 = p0[2], wq03 = p0[3],
          wq04 = p0[4], wq05 = p0[5], wq06 = p0[6], wq07 = p0[7];
    u32x8 wq10 = p1[0], wq11 = p1[1], wq12 = p1[2], wq13 = p1[3],
          wq14 = p1[4], wq15 = p1[5], wq16 = p1[6], wq17 = p1[7];
    float cr0 = rowscale[dir * 1024 + row0];
    float cr1 = rowscale[dir * 1024 + row1];
    float cst = (half == 0) ? c0[dir * HD + e] : 0.0f;
    if (half == 0) {                           // init h -> buffer 1 (read at t=0)
        float hv = h0[dir * HD + e];
        hv = fminf(fmaxf(hv, -1.984375f), 1.984375f);
        int hq = ((int)rintf(hv * 64.f)) & 255;
        int b1 = __shfl_down(hq, 1, 64);
        int b2 = __shfl_down(hq, 2, 64);
        int b3 = __shfl_down(hq, 3, 64);
        if ((lo & 3) == 0)
            h2q[1][e >> 2] = (u32)hq | ((u32)b1 << 8) | ((u32)b2 << 16) | ((u32)b3 << 24);
    }
    __syncthreads();
    const float* Gd = G + (size_t)dir * TT * G4;
    float* Hd = H + (size_t)dir * TT * HD;
    for (int t = 0; t < TT; t++) {
        const u32* hbp = &h2q[(t + 1) & 1][0];         // read buffer
        float g0 = Gd[(size_t)t * G4 + row0];          // issued early
        float g1 = Gd[(size_t)t * G4 + row1];
        int acc0 = 0, acc1 = 0;
        DOTQ2(wq00, wq10, 0)  DOTQ2(wq01, wq11, 8)
        DOTQ2(wq02, wq12, 16) DOTQ2(wq03, wq13, 24)
        DOTQ2(wq04, wq14, 32) DOTQ2(wq05, wq15, 40)
        DOTQ2(wq06, wq16, 48) DOTQ2(wq07, wq17, 56)
        float e0 = (float)acc0 * cr0 + g0;             // i or f preact
        float e1 = (float)acc1 * cr1 + g1;             // g or o preact
        float x0 = sigmf_(e0);                         // sig(i) | sig(f)
        float xs = half ? e1 : (e1 + e1);              // tanh via 2*sig(2x)-1
        float s = sigmf_(xs);
        float x1 = half ? s : (2.0f * s - 1.0f);       // tanh(g) | sig(o)
        float y0 = __shfl_xor(x0, 32, 64);             // partner: sig(f) | sig(i)
        float y1 = __shfl_xor(x1, 32, 64);             // partner: sig(o) | tanh(g)
        if (half == 0) {
            cst = y0 * cst + x0 * x1;                  // sig(f)*c + sig(i)*tanh(g)
            float h = y1 * tanhf_(cst);                // sig(o)*tanh(c)
            Hd[(size_t)t * HD + e] = h;
            int hq = ((int)rintf(h * 64.f)) & 255;     // |h|<1
            int b1 = __shfl_down(hq, 1, 64);
            int b2 = __shfl_down(hq, 2, 64);
            int b3 = __shfl_down(hq, 3, 64);
            if ((lo & 3) == 0)
                h2q[t & 1][e >> 2] = (u32)hq | ((u32)b1 << 8) |
                                     ((u32)b2 << 16) | ((u32)b3 << 24);
        }
        __syncthreads();                               // ONE barrier per step
    }
}

// K3: feats[t][n] = hf[t]·w_out[n][0:256] + hb_scan[T-1-t]·w_out[n][256:512] + b_out[n]
__global__ __launch_bounds__(256) void feats_kernel(const float* H, const float* w_out,
                                                    const float* b_out, float* feats) {
    int idx = blockIdx.x * blockDim.x + threadIdx.x;
    int t = idx >> 4, n = idx & 15;
    const float* hf = H + (size_t)t * HD;
    const float* hb = H + ((size_t)TT + (TT - 1 - t)) * HD;
    const float* w = w_out + (size_t)n * (2 * HD);
    float a = b_out[n];
    for (int k = 0; k < HD; k += 4) {
        float4 h4 = *((const float4*)&hf[k]);
        float4 w4 = *((const float4*)&w[k]);
        a += h4.x * w4.x + h4.y * w4.y + h4.z * w4.z + h4.w * w4.w;
    }
    for (int k = 0; k < HD; k += 4) {
        float4 h4 = *((const float4*)&hb[k]);
        float4 w4 = *((const float4*)&w[HD + k]);
        a += h4.x * w4.x + h4.y * w4.y + h4.z * w4.z + h4.w * w4.w;
    }
    feats[(size_t)t * NT + n] = a;
}

// K4: Viterbi, 512 threads. Forward scan on wave 0 (unchanged math); backtrack
// PARALLELIZED: the old 2047-hop dependent LDS chase (~100us serial) becomes
// Phase A (31 segs x 16 tags chase 64 steps in parallel) + Phase B (31-step
// serial compose) + Phase C (32 segs reconstruct 64 path entries in parallel).
__global__ __launch_bounds__(512) void viterbi_kernel(const float* feats, const float* trans,
                                                      float* out) {
    __shared__ float fl[4096];              // 16KB: 256 steps x 16 tags
    __shared__ float fvs[NT];
    __shared__ unsigned char bps[TT][NT];   // 32KB
    __shared__ unsigned char Gtab[32 * 16]; // seg tag-maps (segs 1..31)
    __shared__ unsigned char Bnd[32];       // segment boundary tags
    __shared__ int bt_sh;
    int tid = threadIdx.x;
    int lane = tid & 63;
    int n = lane >> 2, pg = lane & 3;
    float4 tr4 = *((const float4*)&trans[n * NT + pg * 4]);
    float vft = (n == START_TAG) ? 0.0f : NEGV;
    for (int c = 0; c < TT / 256; c++) {
        const float4* src = (const float4*)(feats + c * 4096);
        for (int i = tid; i < 1024; i += 512) ((float4*)fl)[i] = src[i];
        __syncthreads();
        if (tid < 64) {
            for (int tt = 0; tt < 256; tt++) {
                int t = c * 256 + tt;
                float f0 = __shfl(vft, ((pg << 2) + 0) << 2, 64);
                float f1 = __shfl(vft, ((pg << 2) + 1) << 2, 64);
                float f2 = __shfl(vft, ((pg << 2) + 2) << 2, 64);
                float f3 = __shfl(vft, ((pg << 2) + 3) << 2, 64);
                float ft = fl[tt * 16 + n];
                float v = f0 + tr4.x; int bi = pg * 4 + 0;
                float v1 = f1 + tr4.y; if (v1 > v) { v = v1; bi = pg * 4 + 1; }
                float v2 = f2 + tr4.z; if (v2 > v) { v = v2; bi = pg * 4 + 2; }
                float v3 = f3 + tr4.w; if (v3 > v) { v = v3; bi = pg * 4 + 3; }
#pragma unroll
                for (int m = 1; m <= 2; m <<= 1) {   // first-index tie-break
                    float ov = __shfl_xor(v, m, 64);
                    int ob = __shfl_xor(bi, m, 64);
                    if (ov > v || (ov == v && ob < bi)) { v = ov; bi = ob; }
                }
                if (pg == 0) bps[t][n] = (unsigned char)bi;
                vft = v + ft;
            }
        }
        __syncthreads();
    }
    if (tid < 64 && (lane & 3) == 0) fvs[n] = vft;
    __syncthreads();
    if (tid == 0) {
        float best = -3.0e38f; int bt = 0;
        for (int p = 0; p < NT; p++) {
            float tv = fvs[p] + trans[STOP_TAG * NT + p];
            if (tv > best) { best = tv; bt = p; }
        }
        out[0] = best;
        bt_sh = bt;
    }
    __syncthreads();
    // Phase A: seg s=1..31, start tag tg: chase 64 steps -> Gtab[s][tg]
    if (tid < 496) {
        int seg = 1 + (tid >> 4), tg = tid & 15;
        int x = tg;
        for (int k = 63; k >= 0; k--) x = bps[seg * 64 + k][x];
        Gtab[seg * 16 + tg] = (unsigned char)x;
    }
    __syncthreads();
    // Phase B: serial compose of 31 segment maps
    if (tid == 0) {
        int x = bt_sh;
        Bnd[31] = (unsigned char)x;
        for (int s = 31; s >= 1; s--) { x = Gtab[s * 16 + x]; Bnd[s - 1] = (unsigned char)x; }
    }
    __syncthreads();
    // Phase C: 32 segments reconstruct path[64s .. 64s+63] in parallel
    if (tid < 32) {
        int s = tid;
        int x = Bnd[s];
        out[1 + s * 64 + 63] = (float)x;
        for (int k = 63; k >= 1; k--) {
            x = bps[s * 64 + k][x];
            out[1 + s * 64 + k - 1] = (float)x;
        }
    }
}

extern "C" void kernel_launch(void* const* d_in, const int* in_sizes, int n_in,
                              void* d_out, int out_size, void* d_ws, size_t ws_size,
                              hipStream_t stream) {
    const int* sent = (const int*)d_in[0];
    const float* embed = (const float*)d_in[1];
    const float* wih_f = (const float*)d_in[2];
    const float* whh_f = (const float*)d_in[3];
    const float* b_f = (const float*)d_in[4];
    const float* wih_b = (const float*)d_in[5];
    const float* whh_b = (const float*)d_in[6];
    const float* b_b = (const float*)d_in[7];
    const float* w_out = (const float*)d_in[8];
    const float* b_out = (const float*)d_in[9];
    const float* trans = (const float*)d_in[10];
    const float* h0 = (const float*)d_in[11];
    const float* c0 = (const float*)d_in[12];
    float* out = (float*)d_out;
    char* ws = (char*)d_ws;

    float* G = (float*)(ws);                                    // 16MB
    float* H = (float*)(ws + (size_t)16 * 1024 * 1024);         // 4MB
    float* feats = (float*)(ws + (size_t)20 * 1024 * 1024);     // 128KB
    u32* wreg8 = (u32*)(ws + (size_t)21 * 1024 * 1024);         // 512KB
    float* rowscale = (float*)(ws + (size_t)22 * 1024 * 1024);  // 8KB

    pack_q8<<<dim3(512), 256, 0, stream>>>(whh_f, whh_b, wreg8, rowscale);
    input_gemm<<<dim3(TT / 16, G4 / 256, 2), 256, 0, stream>>>(sent, embed, wih_f, b_f,
                                                               wih_b, b_b, G);
    lstm_rec<<<dim3(2), 512, 0, stream>>>(wreg8, rowscale, G, h0, c0, H);
    feats_kernel<<<dim3(TT * NT / 256), 256, 0, stream>>>(H, w_out, b_out, feats);
    viterbi_kernel<<<dim3(1), 512, 0, stream>>>(feats, trans, out);
}

// Round 15
// 2097.332 us; speedup vs baseline: 1.2828x; 1.2828x over previous
//
#include <hip/hip_runtime.h>

typedef unsigned int u32;
typedef u32 u32x8 __attribute__((ext_vector_type(8)));

#define TT 2048
#define HD 256
#define G4 1024
#define NT 16
#define START_TAG 14
#define STOP_TAG 15
#define NEGV (-10000.0f)

__device__ __forceinline__ int sdot4e(u32 a, u32 b, int c) {
#if __has_builtin(__builtin_amdgcn_sdot4)
    return __builtin_amdgcn_sdot4((int)a, (int)b, c, false);
#else
    c += (int)(signed char)(a & 255) * (int)(signed char)(b & 255);
    c += (int)(signed char)((a >> 8) & 255) * (int)(signed char)((b >> 8) & 255);
    c += (int)(signed char)((a >> 16) & 255) * (int)(signed char)((b >> 16) & 255);
    c += (int)(signed char)(a >> 24) * (int)(signed char)(b >> 24);
    return c;
#endif
}
__device__ __forceinline__ float sigmf_(float x) { return 1.0f / (1.0f + __expf(-x)); }
__device__ __forceinline__ float tanhf_(float x) {
    float e = __expf(-2.0f * fabsf(x));
    return copysignf((1.0f - e) / (1.0f + e), x);
}

// K0: quantize w_hh to int8, per-row scale -> wreg8[dir][row][64] + rowscale.
__global__ __launch_bounds__(256) void pack_q8(const float* whh_f, const float* whh_b,
                                               u32* wreg8, float* rowscale) {
    int lane = threadIdx.x & 63;
    int row = blockIdx.x * 4 + (threadIdx.x >> 6);   // 0..2047
    int dir = row >> 10, r = row & 1023;
    const float* w = (dir ? whh_b : whh_f) + (size_t)r * HD + lane * 4;
    float4 v = *((const float4*)w);
    float m = fmaxf(fmaxf(fabsf(v.x), fabsf(v.y)), fmaxf(fabsf(v.z), fabsf(v.w)));
    for (int off = 1; off < 64; off <<= 1) m = fmaxf(m, __shfl_xor(m, off, 64));
    float invs = m > 0.f ? 127.f / m : 0.f;
    int q0 = (int)rintf(v.x * invs), q1 = (int)rintf(v.y * invs);
    int q2 = (int)rintf(v.z * invs), q3 = (int)rintf(v.w * invs);
    u32 pk = (u32)(q0 & 255) | ((u32)(q1 & 255) << 8) |
             ((u32)(q2 & 255) << 16) | ((u32)(q3 & 255) << 24);
    wreg8[((size_t)(dir * 1024 + r)) * 64 + lane] = pk;
    if (lane == 0) rowscale[dir * 1024 + r] = m * (1.0f / (127.f * 64.f));
}

// K1: G[dir][t][r] = dot(embed[sent[.]], w_ih[r]) + b[r]  (f32 exact).
// TWO output columns per thread (r, r+256) share each X broadcast read ->
// DS:VALU per kc = 16 ds_read_b128 : 128 FMA -> VALU-bound (was DS-bound).
__global__ __launch_bounds__(256) void input_gemm(const int* sent, const float* embed,
                                                  const float* wih_f, const float* b_f,
                                                  const float* wih_b, const float* b_b,
                                                  float* G) {
    __shared__ float X[16][HD];   // 16KB
    __shared__ int rows[16];
    int tid = threadIdx.x;
    int dir = blockIdx.z;
    int t0 = blockIdx.x * 16;
    if (tid < 16) {
        int tg = t0 + tid;
        rows[tid] = sent[dir ? (TT - 1 - tg) : tg];
    }
    __syncthreads();
    for (int i = 0; i < 16; i++) X[i][tid] = embed[(size_t)rows[i] * HD + tid];
    __syncthreads();
    int r = blockIdx.y * 512 + tid;     // column A; column B = r+256
    const float* base = dir ? wih_b : wih_f;
    const float* wrowA = base + (size_t)r * HD;
    const float* wrowB = base + (size_t)(r + 256) * HD;
    float accA[16], accB[16];
#pragma unroll
    for (int i = 0; i < 16; i++) { accA[i] = 0.0f; accB[i] = 0.0f; }
    for (int kc = 0; kc < HD / 4; kc++) {
        float4 wa = ((const float4*)wrowA)[kc];
        float4 wb = ((const float4*)wrowB)[kc];
#pragma unroll
        for (int i = 0; i < 16; i++) {
            float4 x4 = *((const float4*)&X[i][kc * 4]);
            accA[i] += wa.x * x4.x + wa.y * x4.y + wa.z * x4.z + wa.w * x4.w;
            accB[i] += wb.x * x4.x + wb.y * x4.y + wb.z * x4.z + wb.w * x4.w;
        }
    }
    const float* bb = dir ? b_b : b_f;
    float biasA = bb[r], biasB = bb[r + 256];
    for (int i = 0; i < 16; i++) {
        G[((size_t)dir * TT + t0 + i) * G4 + r] = accA[i] + biasA;
        G[((size_t)dir * TT + t0 + i) * G4 + r + 256] = accB[i] + biasB;
    }
}

// two-row int8 dot block vs h broadcast at hbp-style buffer h2q[HB..HB+7]
#define DOTQ2(W0, W1, HB)                                                     \
    {                                                                         \
        uint4 pa = *((const uint4*)&h2q[(HB)]);                               \
        acc0 = sdot4e(W0[0], pa.x, acc0); acc1 = sdot4e(W1[0], pa.x, acc1);   \
        acc0 = sdot4e(W0[1], pa.y, acc0); acc1 = sdot4e(W1[1], pa.y, acc1);   \
        acc0 = sdot4e(W0[2], pa.z, acc0); acc1 = sdot4e(W1[2], pa.z, acc1);   \
        acc0 = sdot4e(W0[3], pa.w, acc0); acc1 = sdot4e(W1[3], pa.w, acc1);   \
        uint4 pb = *((const uint4*)&h2q[(HB) + 4]);                           \
        acc0 = sdot4e(W0[4], pb.x, acc0); acc1 = sdot4e(W1[4], pb.x, acc1);   \
        acc0 = sdot4e(W0[5], pb.y, acc0); acc1 = sdot4e(W1[5], pb.y, acc1);   \
        acc0 = sdot4e(W0[6], pb.z, acc0); acc1 = sdot4e(W1[6], pb.z, acc1);   \
        acc0 = sdot4e(W0[7], pb.w, acc0); acc1 = sdot4e(W1[7], pb.w, acc1);   \
    }

// K2: persistent per-direction LSTM recurrence (R13 verbatim — best measured:
// 1996us). 512 threads, 2 gate rows each; all 128 weight u32 in 16 named u32x8
// SSA values (VGPR+AGPR, scratch-free); int8 v_dot4; two barriers/step.
__global__ __launch_bounds__(512, 1)
void lstm_rec(const u32* wreg8, const float* rowscale,
              const float* G, const float* h0, const float* c0, float* H) {
    __shared__ float fo[2][256];           // sig(f), sig(o)
    __shared__ __align__(16) u32 h2q[64];  // 256 int8 of h (byte j = h[j])
    int tid = threadIdx.x;
    int dir = blockIdx.x;
    const u32x8* p0 = (const u32x8*)(wreg8 + ((size_t)dir * 1024 + tid) * 64);
    const u32x8* p1 = (const u32x8*)(wreg8 + ((size_t)dir * 1024 + tid + 512) * 64);
    u32x8 wq00 = p0[0], wq01 = p0[1], wq02 = p0[2], wq03 = p0[3],
          wq04 = p0[4], wq05 = p0[5], wq06 = p0[6], wq07 = p0[7];
    u32x8 wq10 = p1[0], wq11 = p1[1], wq12 = p1[2], wq13 = p1[3],
          wq14 = p1[4], wq15 = p1[5], wq16 = p1[6], wq17 = p1[7];
    float cr0 = rowscale[dir * 1024 + tid];
    float cr1 = rowscale[dir * 1024 + tid + 512];
    float cst = 0.0f;
    if (tid < 256) {
        cst = c0[dir * HD + tid];
        float hv = h0[dir * HD + tid];
        hv = fminf(fmaxf(hv, -1.984375f), 1.984375f);
        ((signed char*)h2q)[tid] = (signed char)(int)rintf(hv * 64.f);
    }
    __syncthreads();
    const float* Gd = G + (size_t)dir * TT * G4;
    float* Hd = H + (size_t)dir * TT * HD;
    for (int t = 0; t < TT; t++) {
        float g0 = Gd[(size_t)t * G4 + tid];          // issued early
        float g1 = Gd[(size_t)t * G4 + tid + 512];
        int acc0 = 0, acc1 = 0;
        DOTQ2(wq00, wq10, 0)  DOTQ2(wq01, wq11, 8)
        DOTQ2(wq02, wq12, 16) DOTQ2(wq03, wq13, 24)
        DOTQ2(wq04, wq14, 32) DOTQ2(wq05, wq15, 40)
        DOTQ2(wq06, wq16, 48) DOTQ2(wq07, wq17, 56)
        float e0 = (float)acc0 * cr0 + g0;
        float e1 = (float)acc1 * cr1 + g1;
        float x0, x1;
        if (tid >= 256) {                    // e0 = f_j, e1 = o_j  (j = tid-256)
            fo[0][tid - 256] = sigmf_(e0);
            fo[1][tid - 256] = sigmf_(e1);
        } else {                             // e0 = i_j, e1 = g_j
            x0 = sigmf_(e0);
            x1 = tanhf_(e1);
        }
        __syncthreads();
        if (tid < 256) {
            float sf = fo[0][tid], so = fo[1][tid];
            cst = sf * cst + x0 * x1;
            float h = so * tanhf_(cst);
            Hd[(size_t)t * HD + tid] = h;
            ((signed char*)h2q)[tid] = (signed char)(int)rintf(h * 64.f);  // |h|<1
        }
        __syncthreads();
    }
}

// K3: feats[t][n] = hf[t]·w_out[n][0:256] + hb_scan[T-1-t]·w_out[n][256:512] + b_out[n]
__global__ __launch_bounds__(256) void feats_kernel(const float* H, const float* w_out,
                                                    const float* b_out, float* feats) {
    int idx = blockIdx.x * blockDim.x + threadIdx.x;
    int t = idx >> 4, n = idx & 15;
    const float* hf = H + (size_t)t * HD;
    const float* hb = H + ((size_t)TT + (TT - 1 - t)) * HD;
    const float* w = w_out + (size_t)n * (2 * HD);
    float a = b_out[n];
    for (int k = 0; k < HD; k += 4) {
        float4 h4 = *((const float4*)&hf[k]);
        float4 w4 = *((const float4*)&w[k]);
        a += h4.x * w4.x + h4.y * w4.y + h4.z * w4.z + h4.w * w4.w;
    }
    for (int k = 0; k < HD; k += 4) {
        float4 h4 = *((const float4*)&hb[k]);
        float4 w4 = *((const float4*)&w[HD + k]);
        a += h4.x * w4.x + h4.y * w4.y + h4.z * w4.z + h4.w * w4.w;
    }
    feats[(size_t)t * NT + n] = a;
}

// K4a: Viterbi segment matrices (max-plus parallel scan, phase 1).
// Block s (0..31), wave j (0..15): forward-scan segment s's 64 steps from
// one-hot start j -> column j of M_s.  M[s][n][j] = best path sum entering
// the segment at tag j and ending at tag n (feats included).
__global__ __launch_bounds__(1024) void vit_segmat(const float* feats, const float* trans,
                                                   float* Mbuf) {
    int tid = threadIdx.x;
    int lane = tid & 63;
    int col = tid >> 6;             // start column j = wave id
    int s = blockIdx.x;             // segment
    int n = lane >> 2, pg = lane & 3;
    float4 tr4 = *((const float4*)&trans[n * NT + pg * 4]);
    float vft = (n == col) ? 0.0f : NEGV;
    const float* fseg = feats + s * 64 * NT;
    float ftn = fseg[n];
    for (int k = 0; k < 64; k++) {
        float f0 = __shfl(vft, ((pg << 2) + 0) << 2, 64);
        float f1 = __shfl(vft, ((pg << 2) + 1) << 2, 64);
        float f2 = __shfl(vft, ((pg << 2) + 2) << 2, 64);
        float f3 = __shfl(vft, ((pg << 2) + 3) << 2, 64);
        float ft = ftn;
        if (k + 1 < 64) ftn = fseg[(k + 1) * NT + n];
        float v = fmaxf(fmaxf(f0 + tr4.x, f1 + tr4.y), fmaxf(f2 + tr4.z, f3 + tr4.w));
#pragma unroll
        for (int m = 1; m <= 2; m <<= 1) v = fmaxf(v, __shfl_xor(v, m, 64));
        vft = v + ft;
    }
    if (pg == 0) Mbuf[(s * 16 + n) * 16 + col] = vft;
}

// K4b: compose boundaries + rescan with bps + backtrack, one block.
__global__ __launch_bounds__(1024) void vit_solve(const float* feats, const float* trans,
                                                  const float* Mbuf, float* out) {
    __shared__ float Msh[32 * 256];          // 32KB
    __shared__ float Bnd[33][16];            // boundary vectors
    __shared__ unsigned char bps[TT][NT];    // 32KB
    __shared__ unsigned char Gtab[32 * 16];
    __shared__ unsigned char BndT[32];
    __shared__ int bt_sh;
    int tid = threadIdx.x;
    int lane = tid & 63;
    int wv = tid >> 6;
    int n = lane >> 2, pg = lane & 3;
    for (int i = tid; i < 32 * 256 / 4; i += 1024)
        ((float4*)Msh)[i] = ((const float4*)Mbuf)[i];
    __syncthreads();
    // --- wave 0: compose 32 boundary vectors (max-plus matvec chain) ---
    if (wv == 0) {
        float vft = (n == START_TAG) ? 0.0f : NEGV;
        if (pg == 0) Bnd[0][n] = vft;
        for (int s = 0; s < 32; s++) {
            float4 m4 = *((const float4*)&Msh[(s * 16 + n) * 16 + pg * 4]);
            float f0 = __shfl(vft, ((pg << 2) + 0) << 2, 64);
            float f1 = __shfl(vft, ((pg << 2) + 1) << 2, 64);
            float f2 = __shfl(vft, ((pg << 2) + 2) << 2, 64);
            float f3 = __shfl(vft, ((pg << 2) + 3) << 2, 64);
            float v = fmaxf(fmaxf(f0 + m4.x, f1 + m4.y), fmaxf(f2 + m4.z, f3 + m4.w));
#pragma unroll
            for (int m = 1; m <= 2; m <<= 1) v = fmaxf(v, __shfl_xor(v, m, 64));
            vft = v;
            if (pg == 0) Bnd[s + 1][n] = vft;
        }
        if (lane == 0) {
            float best = -3.0e38f; int bt = 0;
            for (int p = 0; p < NT; p++) {
                float tv = Bnd[32][p] + trans[STOP_TAG * NT + p];
                if (tv > best) { best = tv; bt = p; }
            }
            out[0] = best;
            bt_sh = bt;
        }
    }
    __syncthreads();
    // --- 16 waves rescan 2 segments each from exact boundaries, storing bps ---
    float4 tr4 = *((const float4*)&trans[n * NT + pg * 4]);
    for (int rep = 0; rep < 2; rep++) {
        int s = wv + rep * 16;
        float vft = Bnd[s][n];
        const float* fseg = feats + s * 64 * NT;
        float ftn = fseg[n];
        for (int k = 0; k < 64; k++) {
            float f0 = __shfl(vft, ((pg << 2) + 0) << 2, 64);
            float f1 = __shfl(vft, ((pg << 2) + 1) << 2, 64);
            float f2 = __shfl(vft, ((pg << 2) + 2) << 2, 64);
            float f3 = __shfl(vft, ((pg << 2) + 3) << 2, 64);
            float ft = ftn;
            if (k + 1 < 64) ftn = fseg[(k + 1) * NT + n];
            float v = f0 + tr4.x; int bi = pg * 4 + 0;
            float v1 = f1 + tr4.y; if (v1 > v) { v = v1; bi = pg * 4 + 1; }
            float v2 = f2 + tr4.z; if (v2 > v) { v = v2; bi = pg * 4 + 2; }
            float v3 = f3 + tr4.w; if (v3 > v) { v = v3; bi = pg * 4 + 3; }
#pragma unroll
            for (int m = 1; m <= 2; m <<= 1) {   // first-index tie-break
                float ov = __shfl_xor(v, m, 64);
                int ob = __shfl_xor(bi, m, 64);
                if (ov > v || (ov == v && ob < bi)) { v = ov; bi = ob; }
            }
            if (pg == 0) bps[s * 64 + k][n] = (unsigned char)bi;
            vft = v + ft;
        }
    }
    __syncthreads();
    // --- backtrack (R14-verified): segment tag-chases, compose, emit ---
    if (tid < 496) {
        int seg = 1 + (tid >> 4), tg = tid & 15;
        int x = tg;
        for (int k = 63; k >= 0; k--) x = bps[seg * 64 + k][x];
        Gtab[seg * 16 + tg] = (unsigned char)x;
    }
    __syncthreads();
    if (tid == 0) {
        int x = bt_sh;
        BndT[31] = (unsigned char)x;
        for (int s = 31; s >= 1; s--) { x = Gtab[s * 16 + x]; BndT[s - 1] = (unsigned char)x; }
    }
    __syncthreads();
    if (tid < 32) {
        int s = tid;
        int x = BndT[s];
        out[1 + s * 64 + 63] = (float)x;
        for (int k = 63; k >= 1; k--) {
            x = bps[s * 64 + k][x];
            out[1 + s * 64 + k - 1] = (float)x;
        }
    }
}

extern "C" void kernel_launch(void* const* d_in, const int* in_sizes, int n_in,
                              void* d_out, int out_size, void* d_ws, size_t ws_size,
                              hipStream_t stream) {
    const int* sent = (const int*)d_in[0];
    const float* embed = (const float*)d_in[1];
    const float* wih_f = (const float*)d_in[2];
    const float* whh_f = (const float*)d_in[3];
    const float* b_f = (const float*)d_in[4];
    const float* wih_b = (const float*)d_in[5];
    const float* whh_b = (const float*)d_in[6];
    const float* b_b = (const float*)d_in[7];
    const float* w_out = (const float*)d_in[8];
    const float* b_out = (const float*)d_in[9];
    const float* trans = (const float*)d_in[10];
    const float* h0 = (const float*)d_in[11];
    const float* c0 = (const float*)d_in[12];
    float* out = (float*)d_out;
    char* ws = (char*)d_ws;

    float* G = (float*)(ws);                                    // 16MB
    float* H = (float*)(ws + (size_t)16 * 1024 * 1024);         // 4MB
    float* feats = (float*)(ws + (size_t)20 * 1024 * 1024);     // 128KB
    u32* wreg8 = (u32*)(ws + (size_t)21 * 1024 * 1024);         // 512KB
    float* rowscale = (float*)(ws + (size_t)22 * 1024 * 1024);  // 8KB
    float* Mbuf = (float*)(ws + (size_t)22 * 1024 * 1024 + 64 * 1024);  // 32KB

    pack_q8<<<dim3(512), 256, 0, stream>>>(whh_f, whh_b, wreg8, rowscale);
    input_gemm<<<dim3(TT / 16, 2, 2), 256, 0, stream>>>(sent, embed, wih_f, b_f,
                                                        wih_b, b_b, G);
    lstm_rec<<<dim3(2), 512, 0, stream>>>(wreg8, rowscale, G, h0, c0, H);
    feats_kernel<<<dim3(TT * NT / 256), 256, 0, stream>>>(H, w_out, b_out, feats);
    vit_segmat<<<dim3(32), 1024, 0, stream>>>(feats, trans, Mbuf);
    vit_solve<<<dim3(1), 1024, 0, stream>>>(feats, trans, Mbuf, out);
}